// Round 2
// baseline (216.608 us; speedup 1.0000x reference)
//
#include <hip/hip_runtime.h>
#include <stdint.h>

// ---------------------------------------------------------------------------
// SNN EMNIST forward: T=10, B=4096, IN=784, HID=256, NCLS=47
// R13 (resubmit; previous round was an infra failure, not a kernel result):
// DE-FUSE the threefry spikegen from the GEMM.
//  - spikegen_k: packed spike bits [25][40960] u32 (4.096 MB, fits the
//    existing workspace gap) at full occupancy (4000 blocks, no LDS/barriers).
//    Hash VALU was serialized against MFMA inside a 640-block (2.5/CU) kernel
//    at 51% VALUBusy; standalone it runs at issue rate (~30 µs floor).
//  - fused_gemm_k: hash replaced by 1 u32 load + ~20-op bit->bf16 expand;
//    staging/swizzle/MFMA order UNCHANGED -> I_all bitwise identical.
//  - scanout_k: re-gridded 256 -> 1024 blocks (4 batch rows each); identical
//    per-thread scan order and ascending-h fmaf chain -> same numerics.
// Expected absmax unchanged: 4.882812e-4.
// ---------------------------------------------------------------------------

#define T_STEPS 10
#define BATCH   4096
#define IN_DIM  784
#define HID     256
#define NCLS    47
#define NROWS   (T_STEPS * BATCH)        // 40960
#define KWORDS  25                       // ceil(784/32)
#define KPAD    800                      // 25*32

// d_ws layout (bytes):
//   [0, 41943040)          I_all  : float [40960][256]
//   [41943040, 46039040)   spikes : u32 [25][40960] (packed bits, bit j = k)
//   [46039040, ...)        W1{hi,mid,lo}T : bf16 [256][800], 409600 B each
#define WS_IALL_OFF 0u
#define WS_SPK_OFF  41943040u
#define WS_W1HI_OFF 46039040u
#define WS_W1MD_OFF (46039040u + 409600u)
#define WS_W1LO_OFF (46039040u + 819200u)

typedef __attribute__((ext_vector_type(8))) short    bf16x8;
typedef __attribute__((ext_vector_type(4))) float    f32x4;
typedef __attribute__((ext_vector_type(4))) uint32_t u32x4;

__device__ __forceinline__ uint32_t rotl32(uint32_t x, uint32_t r) {
    return __builtin_amdgcn_alignbit(x, x, 32u - r);
}

// JAX threefry2x32, key=(0,42), partitionable scheme: out = o0^o1, x0=0, x1=i.
__device__ __forceinline__ uint32_t tf_hash(uint32_t lo) {
    const uint32_t ks1 = 42u;
    const uint32_t ks2 = 0x1BD11BDAu ^ 42u;
    uint32_t x0 = 0u;
    uint32_t x1 = lo + ks1;
#define TF_RND(r) { x0 += x1; x1 = rotl32(x1, r); x1 ^= x0; }
    TF_RND(13) TF_RND(15) TF_RND(26) TF_RND(6)
    x0 += ks1; x1 += ks2 + 1u;
    TF_RND(17) TF_RND(29) TF_RND(16) TF_RND(24)
    x0 += ks2; x1 += 2u;                       // ks0 == 0
    TF_RND(13) TF_RND(15) TF_RND(26) TF_RND(6)
    x1 += ks1 + 3u;                            // x0 += ks0 is a no-op
    TF_RND(17) TF_RND(29) TF_RND(16) TF_RND(24)
    x0 += ks1; x1 += ks2 + 4u;
    TF_RND(13) TF_RND(15) TF_RND(26) TF_RND(6)
    x0 += ks2; x1 += 5u;                       // ks0 == 0
#undef TF_RND
    return x0 ^ x1;
}

// ---------------------------------------------------------------------------
// Kernel B0: split W1 (f32 [784][256]) into transposed bf16 hi/mid/lo
// [256][800]. EXACT: hi+mid+lo == w bitwise.
// ---------------------------------------------------------------------------
__global__ __launch_bounds__(256) void splitk_k(
        const float* __restrict__ W1, ushort* __restrict__ hiT,
        ushort* __restrict__ midT, ushort* __restrict__ loT) {
    int n = blockIdx.x;                  // 0..255
    for (int k = threadIdx.x; k < KPAD; k += 256) {
        float w = (k < IN_DIM) ? W1[k * HID + n] : 0.0f;
        uint32_t u = __float_as_uint(w);
        uint32_t hb = (u + 0x7FFFu + ((u >> 16) & 1u)) >> 16;    // RNE to bf16
        float hf = __uint_as_float(hb << 16);
        float r1 = w - hf;                                       // exact
        uint32_t u1 = __float_as_uint(r1);
        uint32_t mb = (u1 + 0x7FFFu + ((u1 >> 16) & 1u)) >> 16;  // RNE
        float mf2 = __uint_as_float(mb << 16);
        float r2 = r1 - mf2;                                     // exact
        uint32_t u2 = __float_as_uint(r2);
        uint32_t lb = (u2 + 0x7FFFu + ((u2 >> 16) & 1u)) >> 16;  // exact fit
        hiT [n * KPAD + k] = (ushort)hb;
        midT[n * KPAD + k] = (ushort)mb;
        loT [n * KPAD + k] = (ushort)lb;
    }
}

// ---------------------------------------------------------------------------
// Kernel S: standalone spikegen. One thread per (row, kw) word: 32 hashes
// (16 on the kw=24 tail; bits 16..31 stay 0 = the old zero-pad path).
// Bit j of word (row,kw) = spike at k = kw*32+j, identical compare expr to
// the old in-gemm path. Layout [kw][row] -> coalesced 1KB writes per wave,
// and the gemm reads 64 consecutive words per slab.
// grid = (160, 25): blockIdx.y = kw (uniform per block -> no divergence).
// ---------------------------------------------------------------------------
__global__ __launch_bounds__(256) void spikegen_k(
        const float* __restrict__ x, uint32_t* __restrict__ spk) {
    const int kw  = blockIdx.y;
    const int row = (blockIdx.x << 8) + threadIdx.x;     // 0..40959, = t*4096+b
    const int b   = row & (BATCH - 1);
    const int k0  = kw << 5;
    const float* xp = x + (size_t)b * IN_DIM + k0;
    // global element index i = t*B*IN + b*IN + k = row*784 + k
    const uint32_t ib = (uint32_t)row * (uint32_t)IN_DIM + (uint32_t)k0;
    const int ng = (kw == KWORDS - 1) ? 2 : 4;           // uniform per block
    uint32_t wbits = 0u;
    for (int g = 0; g < ng; ++g) {
        float4 xa = *(const float4*)(xp + (g << 3));
        float4 xb = *(const float4*)(xp + (g << 3) + 4);
        uint32_t base = ib + (uint32_t)(g << 3);
        uint32_t bits = 0u;
        bits |= ((float)(tf_hash(base + 0u) >> 9) < xa.x * 8388608.0f) ? 1u   : 0u;
        bits |= ((float)(tf_hash(base + 1u) >> 9) < xa.y * 8388608.0f) ? 2u   : 0u;
        bits |= ((float)(tf_hash(base + 2u) >> 9) < xa.z * 8388608.0f) ? 4u   : 0u;
        bits |= ((float)(tf_hash(base + 3u) >> 9) < xa.w * 8388608.0f) ? 8u   : 0u;
        bits |= ((float)(tf_hash(base + 4u) >> 9) < xb.x * 8388608.0f) ? 16u  : 0u;
        bits |= ((float)(tf_hash(base + 5u) >> 9) < xb.y * 8388608.0f) ? 32u  : 0u;
        bits |= ((float)(tf_hash(base + 6u) >> 9) < xb.z * 8388608.0f) ? 64u  : 0u;
        bits |= ((float)(tf_hash(base + 7u) >> 9) < xb.w * 8388608.0f) ? 128u : 0u;
        wbits |= bits << (g << 3);
    }
    spk[(size_t)kw * NROWS + row] = wbits;
}

// ---------------------------------------------------------------------------
// GEMM: I_all = spikes @ W1 + b1 (3-plane exact bf16 split of W1).
// Same block/wave/tile geometry, LDS swizzle, staging and MFMA accumulation
// order as R12 -> bitwise-identical I_all. Only change: the per-slab A
// fragment comes from a prefetched spike word (1 dword load + ~20 VALU
// bit-expand) instead of 8 inline threefry hashes (~600 VALU).
// ---------------------------------------------------------------------------
#define LDS_A  0
#define LDS_BH 4096
#define LDS_BM 20480
#define LDS_BL 36864

__global__ __launch_bounds__(256, 3) void fused_gemm_k(
        const ushort* __restrict__ hiT, const ushort* __restrict__ midT,
        const ushort* __restrict__ loT, const float* __restrict__ b1,
        const uint32_t* __restrict__ spk, float* __restrict__ I_all) {
    __shared__ __align__(16) char lds[53248];

    const int tid = threadIdx.x;
    const int l   = tid & 63;
    const int wv  = tid >> 6;
    const int m0  = blockIdx.x << 6;

    f32x4 acc[4][4] = {};

    // fragment read addressing (shared swizzle sig for A and B)
    const int q   = l >> 4;
    const int sig = q ^ (l & 3) ^ ((l >> 2) & 3);
    const int a_base = LDS_A + ((l & 15) << 6) + (sig << 4);
    const int b_off  = (((wv << 6) + (l & 15)) << 6) + (sig << 4);

    // ---- loop-invariant staging addresses (hoisted) ----
    const ushort* hi_p[4];
    const ushort* md_p[4];
    const ushort* lo_p[4];
    int ldst_c[4];
#pragma unroll
    for (int i = 0; i < 4; ++i) {
        int s  = (wv << 8) + (i << 6) + l;
        int n  = s >> 2;
        int qs = s & 3;
        int qd = qs ^ (n & 3) ^ ((n >> 2) & 3);
        size_t eoff = (size_t)n * KPAD + ((size_t)qd << 3);
        hi_p[i] = hiT  + eoff;
        md_p[i] = midT + eoff;
        lo_p[i] = loT  + eoff;
        ldst_c[i] = ((wv << 8) + (i << 6)) << 4;
    }

    // A-expansion thread mapping: row er (0..63), byte-group eq (0..3)
    const int er = tid >> 2;
    const int eq = tid & 3;
    const int ea = LDS_A + (er << 6) + ((eq ^ (er & 3) ^ ((er >> 2) & 3)) << 4);

    // spike word stream for this row: spk[kw*NROWS + (m0+er)], prefetched
    const uint32_t* sp = spk + (size_t)(m0 + er);
    uint32_t wcur = sp[0];

    for (int kw = 0; kw < KWORDS; ++kw) {
        __syncthreads();   // previous compute done with LDS

        // --- stage Bhi/Bmid/Blo K-slab (hoisted pointers) ---
#pragma unroll
        for (int i = 0; i < 4; ++i) {
            __builtin_amdgcn_global_load_lds(
                (const __attribute__((address_space(1))) void*)hi_p[i],
                (__attribute__((address_space(3))) void*)(lds + LDS_BH + ldst_c[i]),
                16, 0, 0);
            __builtin_amdgcn_global_load_lds(
                (const __attribute__((address_space(1))) void*)md_p[i],
                (__attribute__((address_space(3))) void*)(lds + LDS_BM + ldst_c[i]),
                16, 0, 0);
            __builtin_amdgcn_global_load_lds(
                (const __attribute__((address_space(1))) void*)lo_p[i],
                (__attribute__((address_space(3))) void*)(lds + LDS_BL + ldst_c[i]),
                16, 0, 0);
            hi_p[i] += 32;  md_p[i] += 32;  lo_p[i] += 32;
        }

        // --- prefetch next slab's spike word (hidden under MFMA section) ---
        sp += NROWS;
        uint32_t wnext = (kw < KWORDS - 1) ? sp[0] : 0u;

        // --- expand 8 spike bits -> bf16 A fragment (16 B) ---
        // bit (eq*8 + 2p)   -> low  bf16 of v[p] (0x3F80 = 1.0bf16)
        // bit (eq*8 + 2p+1) -> high bf16 of v[p]
        {
            uint32_t byt = (wcur >> (eq << 3)) & 0xffu;
            u32x4 v;
            v.x = ((byt & 1u)   ? 0x3F80u : 0u) | ((byt & 2u)   ? 0x3F800000u : 0u);
            v.y = ((byt & 4u)   ? 0x3F80u : 0u) | ((byt & 8u)   ? 0x3F800000u : 0u);
            v.z = ((byt & 16u)  ? 0x3F80u : 0u) | ((byt & 32u)  ? 0x3F800000u : 0u);
            v.w = ((byt & 64u)  ? 0x3F80u : 0u) | ((byt & 128u) ? 0x3F800000u : 0u);
            *(u32x4*)(lds + ea) = v;   // kw=24 tail bytes are 0 -> zero pad
        }

        __syncthreads();   // A visible + global_load_lds drained

        // --- compute: 4 mtiles x 4 ntiles x (hi,mid,lo) = 48 MFMA ---
        bf16x8 af[4];
#pragma unroll
        for (int mt = 0; mt < 4; ++mt)
            af[mt] = *(const bf16x8*)(lds + a_base + (mt << 10));
#pragma unroll
        for (int nt = 0; nt < 4; ++nt) {
            bf16x8 bh = *(const bf16x8*)(lds + LDS_BH + b_off + (nt << 10));
            bf16x8 bm = *(const bf16x8*)(lds + LDS_BM + b_off + (nt << 10));
            bf16x8 bl = *(const bf16x8*)(lds + LDS_BL + b_off + (nt << 10));
#pragma unroll
            for (int mt = 0; mt < 4; ++mt) {
                acc[mt][nt] = __builtin_amdgcn_mfma_f32_16x16x32_bf16(af[mt], bh, acc[mt][nt], 0, 0, 0);
                acc[mt][nt] = __builtin_amdgcn_mfma_f32_16x16x32_bf16(af[mt], bm, acc[mt][nt], 0, 0, 0);
                acc[mt][nt] = __builtin_amdgcn_mfma_f32_16x16x32_bf16(af[mt], bl, acc[mt][nt], 0, 0, 0);
            }
        }
        wcur = wnext;
    }

    // --- epilogue: acc -> I_all (+ b1) ---
    const int c0 = l & 15;
    float b1v[4];
#pragma unroll
    for (int nt = 0; nt < 4; ++nt)
        b1v[nt] = b1[(wv << 6) + (nt << 4) + c0];
#pragma unroll
    for (int mt = 0; mt < 4; ++mt) {
#pragma unroll
        for (int nt = 0; nt < 4; ++nt) {
            int col = (wv << 6) + (nt << 4) + c0;
#pragma unroll
            for (int r = 0; r < 4; ++r) {
                int row = m0 + (mt << 4) + (q << 2) + r;
                I_all[(size_t)row * HID + col] = acc[mt][nt][r] + b1v[nt];
            }
        }
    }
}

// ---------------------------------------------------------------------------
// Fused LIF scan + readout: per block, 4 batch rows (1024 blocks = 4/CU,
// was 256 = 1/CU latency-starved).
// Phase 1: thread h scans 4 rows over t (exact reference op order) -> g in
// LDS. Phase 2: wave wv -> row b0+wv, lane c<47: out = sum_h g[b][h]*Wr[h][c]
// (+ br*(1-2^-10)), h ascending — identical fmaf chain to R12.
// ---------------------------------------------------------------------------
__global__ __launch_bounds__(256) void scanout_k(
        const float* __restrict__ I_all, const float* __restrict__ Wr,
        const float* __restrict__ br, float* __restrict__ out) {
    __shared__ float gl[4 * 256];        // 4 KB
    const int tid = threadIdx.x;
    const int b0  = blockIdx.x << 2;

#pragma unroll
    for (int b = 0; b < 4; ++b) {
        const float* p = I_all + ((size_t)(b0 + b) << 8) + tid;
        float v = 0.f, ga = 0.f, wt = 0.0009765625f;   // 2^-10
#pragma unroll
        for (int t = 0; t < T_STEPS; ++t) {
            float I = p[(size_t)t * BATCH * HID];
            v = v + (I - v) * 0.5f;
            if (v >= 1.0f) { ga += wt; v = 0.f; }
            wt += wt;
        }
        gl[(b << 8) + tid] = ga;
    }
    __syncthreads();

    const int wv = tid >> 6;             // wave -> batch row b0+wv
    const int c  = tid & 63;
    if (c >= NCLS) return;
    const float* gb = &gl[wv << 8];
    float acc = 0.f;
    for (int h4 = 0; h4 < 64; ++h4) {
        float w0 = Wr[((h4 << 2) + 0) * NCLS + c];
        float w1 = Wr[((h4 << 2) + 1) * NCLS + c];
        float w2 = Wr[((h4 << 2) + 2) * NCLS + c];
        float w3 = Wr[((h4 << 2) + 3) * NCLS + c];
        float4 gg = *(const float4*)&gb[h4 << 2];
        acc = fmaf(gg.x, w0, acc);
        acc = fmaf(gg.y, w1, acc);
        acc = fmaf(gg.z, w2, acc);
        acc = fmaf(gg.w, w3, acc);
    }
    float brv = br[c] * 0.9990234375f;
    out[(b0 + wv) * NCLS + c] = acc + brv;
}

extern "C" void kernel_launch(void* const* d_in, const int* in_sizes, int n_in,
                              void* d_out, int out_size, void* d_ws, size_t ws_size,
                              hipStream_t stream) {
    const float* x  = (const float*)d_in[0];
    const float* W1 = (const float*)d_in[1];
    const float* b1 = (const float*)d_in[2];
    const float* Wr = (const float*)d_in[3];
    const float* br = (const float*)d_in[4];
    float* out = (float*)d_out;

    float*    I_all = (float*)   ((char*)d_ws + WS_IALL_OFF);
    uint32_t* spkw  = (uint32_t*)((char*)d_ws + WS_SPK_OFF);
    ushort*   w1hi  = (ushort*)  ((char*)d_ws + WS_W1HI_OFF);
    ushort*   w1md  = (ushort*)  ((char*)d_ws + WS_W1MD_OFF);
    ushort*   w1lo  = (ushort*)  ((char*)d_ws + WS_W1LO_OFF);

    splitk_k<<<HID, 256, 0, stream>>>(W1, w1hi, w1md, w1lo);
    spikegen_k<<<dim3(NROWS / 256, KWORDS), 256, 0, stream>>>(x, spkw);
    fused_gemm_k<<<NROWS / 64, 256, 0, stream>>>(w1hi, w1md, w1lo, b1, spkw, I_all);
    scanout_k<<<BATCH / 4, 256, 0, stream>>>(I_all, Wr, br, out);
}

// Round 3
// 191.955 us; speedup vs baseline: 1.1284x; 1.1284x over previous
//
#include <hip/hip_runtime.h>
#include <stdint.h>

// ---------------------------------------------------------------------------
// SNN EMNIST forward: T=10, B=4096, IN=784, HID=256, NCLS=47
// R14: gemm restructure. M-tile 64 -> 160 (grid 256 = exactly 1 block/CU,
// no 3-vs-2 imbalance), 512 threads = 8 waves (2Mx4N, wave=80x64),
// DOUBLE-BUFFERED A and B with ONE __syncthreads per K-slab (T3 2-phase:
// issue next-slab loads -> MFMA current -> barrier drains; load latency
// hides under the ~2.3K-cycle MFMA phase). B L2 traffic 768->307 MB.
// Per-element accumulation order unchanged (kw asc x hi,mid,lo) -> I_all
// bitwise identical -> absmax stays 4.882812e-4.
// spikegen: runtime ng loop -> two compile-time unrolled paths (same bits).
// splitk/scanout unchanged for attribution.
// ---------------------------------------------------------------------------

#define T_STEPS 10
#define BATCH   4096
#define IN_DIM  784
#define HID     256
#define NCLS    47
#define NROWS   (T_STEPS * BATCH)        // 40960
#define KWORDS  25                       // ceil(784/32)
#define KPAD    800                      // 25*32
#define M_TILE  160

// d_ws layout (bytes):
//   [0, 41943040)          I_all  : float [40960][256]
//   [41943040, 46039040)   spikes : u32 [25][40960] (packed bits, bit j = k)
//   [46039040, ...)        W1{hi,mid,lo}T : bf16 [256][800], 409600 B each
#define WS_IALL_OFF 0u
#define WS_SPK_OFF  41943040u
#define WS_W1HI_OFF 46039040u
#define WS_W1MD_OFF (46039040u + 409600u)
#define WS_W1LO_OFF (46039040u + 819200u)

typedef __attribute__((ext_vector_type(8))) short    bf16x8;
typedef __attribute__((ext_vector_type(4))) float    f32x4;
typedef __attribute__((ext_vector_type(4))) uint32_t u32x4;

__device__ __forceinline__ uint32_t rotl32(uint32_t x, uint32_t r) {
    return __builtin_amdgcn_alignbit(x, x, 32u - r);
}

// JAX threefry2x32, key=(0,42), partitionable scheme: out = o0^o1, x0=0, x1=i.
__device__ __forceinline__ uint32_t tf_hash(uint32_t lo) {
    const uint32_t ks1 = 42u;
    const uint32_t ks2 = 0x1BD11BDAu ^ 42u;
    uint32_t x0 = 0u;
    uint32_t x1 = lo + ks1;
#define TF_RND(r) { x0 += x1; x1 = rotl32(x1, r); x1 ^= x0; }
    TF_RND(13) TF_RND(15) TF_RND(26) TF_RND(6)
    x0 += ks1; x1 += ks2 + 1u;
    TF_RND(17) TF_RND(29) TF_RND(16) TF_RND(24)
    x0 += ks2; x1 += 2u;                       // ks0 == 0
    TF_RND(13) TF_RND(15) TF_RND(26) TF_RND(6)
    x1 += ks1 + 3u;                            // x0 += ks0 is a no-op
    TF_RND(17) TF_RND(29) TF_RND(16) TF_RND(24)
    x0 += ks1; x1 += ks2 + 4u;
    TF_RND(13) TF_RND(15) TF_RND(26) TF_RND(6)
    x0 += ks2; x1 += 5u;                       // ks0 == 0
#undef TF_RND
    return x0 ^ x1;
}

// ---------------------------------------------------------------------------
// Kernel B0: split W1 (f32 [784][256]) into transposed bf16 hi/mid/lo
// [256][800]. EXACT: hi+mid+lo == w bitwise.
// ---------------------------------------------------------------------------
__global__ __launch_bounds__(256) void splitk_k(
        const float* __restrict__ W1, ushort* __restrict__ hiT,
        ushort* __restrict__ midT, ushort* __restrict__ loT) {
    int n = blockIdx.x;                  // 0..255
    for (int k = threadIdx.x; k < KPAD; k += 256) {
        float w = (k < IN_DIM) ? W1[k * HID + n] : 0.0f;
        uint32_t u = __float_as_uint(w);
        uint32_t hb = (u + 0x7FFFu + ((u >> 16) & 1u)) >> 16;    // RNE to bf16
        float hf = __uint_as_float(hb << 16);
        float r1 = w - hf;                                       // exact
        uint32_t u1 = __float_as_uint(r1);
        uint32_t mb = (u1 + 0x7FFFu + ((u1 >> 16) & 1u)) >> 16;  // RNE
        float mf2 = __uint_as_float(mb << 16);
        float r2 = r1 - mf2;                                     // exact
        uint32_t u2 = __float_as_uint(r2);
        uint32_t lb = (u2 + 0x7FFFu + ((u2 >> 16) & 1u)) >> 16;  // exact fit
        hiT [n * KPAD + k] = (ushort)hb;
        midT[n * KPAD + k] = (ushort)mb;
        loT [n * KPAD + k] = (ushort)lb;
    }
}

// ---------------------------------------------------------------------------
// Kernel S: standalone spikegen. One thread per (row, kw) word: 32 hashes
// (16 on the kw=24 tail; bits 16..31 stay 0 = zero-pad). Identical compare
// expr / bit placement as before -> same spike words. Runtime ng replaced by
// two compile-time unrolled paths (uniform per block).
// ---------------------------------------------------------------------------
__global__ __launch_bounds__(256) void spikegen_k(
        const float* __restrict__ x, uint32_t* __restrict__ spk) {
    const int kw  = blockIdx.y;
    const int row = (blockIdx.x << 8) + threadIdx.x;     // 0..40959, = t*4096+b
    const int b   = row & (BATCH - 1);
    const int k0  = kw << 5;
    const float* xp = x + (size_t)b * IN_DIM + k0;
    const uint32_t ib = (uint32_t)row * (uint32_t)IN_DIM + (uint32_t)k0;
    uint32_t wbits = 0u;
#define SPIKE_G(g) { \
    float4 xa = *(const float4*)(xp + ((g) << 3)); \
    float4 xb = *(const float4*)(xp + ((g) << 3) + 4); \
    uint32_t base = ib + (uint32_t)((g) << 3); \
    uint32_t bits = 0u; \
    bits |= ((float)(tf_hash(base + 0u) >> 9) < xa.x * 8388608.0f) ? 1u   : 0u; \
    bits |= ((float)(tf_hash(base + 1u) >> 9) < xa.y * 8388608.0f) ? 2u   : 0u; \
    bits |= ((float)(tf_hash(base + 2u) >> 9) < xa.z * 8388608.0f) ? 4u   : 0u; \
    bits |= ((float)(tf_hash(base + 3u) >> 9) < xa.w * 8388608.0f) ? 8u   : 0u; \
    bits |= ((float)(tf_hash(base + 4u) >> 9) < xb.x * 8388608.0f) ? 16u  : 0u; \
    bits |= ((float)(tf_hash(base + 5u) >> 9) < xb.y * 8388608.0f) ? 32u  : 0u; \
    bits |= ((float)(tf_hash(base + 6u) >> 9) < xb.z * 8388608.0f) ? 64u  : 0u; \
    bits |= ((float)(tf_hash(base + 7u) >> 9) < xb.w * 8388608.0f) ? 128u : 0u; \
    wbits |= bits << ((g) << 3); }
    if (kw != KWORDS - 1) {
        SPIKE_G(0) SPIKE_G(1) SPIKE_G(2) SPIKE_G(3)
    } else {
        SPIKE_G(0) SPIKE_G(1)
    }
#undef SPIKE_G
    spk[(size_t)kw * NROWS + row] = wbits;
}

// ---------------------------------------------------------------------------
// GEMM: I_all = spikes @ W1 + b1 (3-plane exact bf16 split of W1).
// Block: 160 rows x 256 cols, 512 threads = 8 waves (2M x 4N), wave = 80x64
// = 5x4 tiles of 16x16x32. Grid 256 = 1 block/CU. A and B double-buffered;
// one __syncthreads per slab: issue B[kw+1] global_load_lds + ds_write
// A[kw+1] into buffer nxt, compute 60 MFMA/wave from buffer cur, barrier
// (implicit vmcnt(0)+lgkmcnt(0) drain), flip. XOR-swizzled 16B quarters
// keep ds_read_b128 <=2-way. Accum order identical to R13.
// LDS: A bufs [0,20480), B bufs 20480 + c*49152 {hi+0, mid+16384, lo+32768}.
// ---------------------------------------------------------------------------
#define LDS_AB0 0
#define LDS_B0  20480
#define B_BUFSZ 49152
#define A_BUFSZ 10240

__global__ __launch_bounds__(512, 2) void fused_gemm_k(
        const ushort* __restrict__ hiT, const ushort* __restrict__ midT,
        const ushort* __restrict__ loT, const float* __restrict__ b1,
        const uint32_t* __restrict__ spk, float* __restrict__ I_all) {
    __shared__ __align__(16) char lds[118784];   // 116 KB, 1 block/CU

    const int tid = threadIdx.x;
    const int l   = tid & 63;
    const int wv  = tid >> 6;        // 0..7
    const int wm  = wv >> 2;         // 0..1 (M half)
    const int wn  = wv & 3;          // 0..3 (N quarter)
    const int m0  = blockIdx.x * M_TILE;

    f32x4 acc[5][4] = {};

    // fragment read addressing (shared swizzle sig for A and B)
    const int q   = l >> 4;
    const int sig = q ^ (l & 3) ^ ((l >> 2) & 3);
    const int a_rd = wm * 5120 + ((l & 15) << 6) + (sig << 4);      // in A buf
    const int b_rd = (((wn << 6) + (l & 15)) << 6) + (sig << 4);    // in plane

    // ---- B staging: 1024 slots of 16B per plane, 2 per thread ----
    // slot s = i*512 + tid; n = s>>2 (col), qd = (s&3)^(n&3)^((n>>2)&3).
    // LDS dst base must be WAVE-UNIFORM (global_load_lds writes lane*16).
    const ushort* hi_p[2];
    const ushort* md_p[2];
    const ushort* lo_p[2];
    int bdst[2];
#pragma unroll
    for (int i = 0; i < 2; ++i) {
        int s  = (i << 9) + tid;
        int n  = s >> 2;
        int qs = s & 3;
        int qd = qs ^ (n & 3) ^ ((n >> 2) & 3);
        size_t eoff = (size_t)n * KPAD + ((size_t)qd << 3);
        hi_p[i] = hiT  + eoff;
        md_p[i] = midT + eoff;
        lo_p[i] = loT  + eoff;
        bdst[i] = ((i << 9) + (wv << 6)) << 4;    // wave-uniform base
    }

    // ---- A expansion: 640 tasks (row 0..159 x eq 0..3); j1 = tid for all,
    // j2 = 512+tid for tid<128 (wave-uniform predicate: waves 0,1 only).
    const int  eq   = tid & 3;
    const int  r1   = tid >> 2;                    // 0..127
    const bool has2 = (tid < 128);
    const int  r2   = 128 + (tid >> 2);            // 128..159 (valid if has2)
    const int  ea1  = (r1 << 6) + ((eq ^ (r1 & 3) ^ ((r1 >> 2) & 3)) << 4);
    const int  ea2  = (r2 << 6) + ((eq ^ (r2 & 3) ^ ((r2 >> 2) & 3)) << 4);

    const uint32_t* sp1 = spk + (size_t)(m0 + r1);
    const uint32_t* sp2 = spk + (size_t)(m0 + (has2 ? r2 : r1));

#define SPIKE_FRAG_STORE(byt, dst) { \
    u32x4 v_; \
    v_.x = (((byt) & 1u)   ? 0x3F80u : 0u) | (((byt) & 2u)   ? 0x3F800000u : 0u); \
    v_.y = (((byt) & 4u)   ? 0x3F80u : 0u) | (((byt) & 8u)   ? 0x3F800000u : 0u); \
    v_.z = (((byt) & 16u)  ? 0x3F80u : 0u) | (((byt) & 32u)  ? 0x3F800000u : 0u); \
    v_.w = (((byt) & 64u)  ? 0x3F80u : 0u) | (((byt) & 128u) ? 0x3F800000u : 0u); \
    *(u32x4*)(dst) = v_; }

#define STAGE_B(koff, bbase) \
    _Pragma("unroll") \
    for (int i = 0; i < 2; ++i) { \
        __builtin_amdgcn_global_load_lds( \
            (const __attribute__((address_space(1))) void*)(hi_p[i] + (koff)), \
            (__attribute__((address_space(3))) void*)(lds + (bbase) + bdst[i]), \
            16, 0, 0); \
        __builtin_amdgcn_global_load_lds( \
            (const __attribute__((address_space(1))) void*)(md_p[i] + (koff)), \
            (__attribute__((address_space(3))) void*)(lds + (bbase) + 16384 + bdst[i]), \
            16, 0, 0); \
        __builtin_amdgcn_global_load_lds( \
            (const __attribute__((address_space(1))) void*)(lo_p[i] + (koff)), \
            (__attribute__((address_space(3))) void*)(lds + (bbase) + 32768 + bdst[i]), \
            16, 0, 0); \
    }

    // ---- prologue: stage slab 0 into buffers 0, prefetch slab-1 words ----
    uint32_t w1c = sp1[0];
    uint32_t w2c = has2 ? sp2[0] : 0u;
    STAGE_B(0, LDS_B0)
    SPIKE_FRAG_STORE((w1c >> (eq << 3)) & 0xffu, lds + ea1)
    if (has2) SPIKE_FRAG_STORE((w2c >> (eq << 3)) & 0xffu, lds + ea2)
    uint32_t w1n = sp1[NROWS];
    uint32_t w2n = has2 ? sp2[NROWS] : 0u;
    __syncthreads();

    int cur = 0;
#pragma unroll 1
    for (int kw = 0; kw < KWORDS; ++kw) {
        const int nxt = cur ^ 1;
        if (kw < KWORDS - 1) {
            // issue next slab's B loads + A frag writes into buffer nxt
            const int koff = (kw + 1) << 5;           // +32 elems per slab
            STAGE_B(koff, LDS_B0 + nxt * B_BUFSZ)
            SPIKE_FRAG_STORE((w1n >> (eq << 3)) & 0xffu,
                             lds + nxt * A_BUFSZ + ea1)
            if (has2) SPIKE_FRAG_STORE((w2n >> (eq << 3)) & 0xffu,
                                       lds + nxt * A_BUFSZ + ea2)
            if (kw < KWORDS - 2) {
                w1n = sp1[(size_t)(kw + 2) * NROWS];
                if (has2) w2n = sp2[(size_t)(kw + 2) * NROWS];
            }
        }

        // --- compute slab kw from buffer cur: 5x4x3 = 60 MFMA / wave ---
        const char* A = lds + cur * A_BUFSZ;
        const char* B = lds + LDS_B0 + cur * B_BUFSZ;
        bf16x8 af[5];
#pragma unroll
        for (int mt = 0; mt < 5; ++mt)
            af[mt] = *(const bf16x8*)(A + a_rd + (mt << 10));
#pragma unroll
        for (int nt = 0; nt < 4; ++nt) {
            bf16x8 bh = *(const bf16x8*)(B + b_rd + (nt << 10));
            bf16x8 bm = *(const bf16x8*)(B + 16384 + b_rd + (nt << 10));
            bf16x8 bl = *(const bf16x8*)(B + 32768 + b_rd + (nt << 10));
#pragma unroll
            for (int mt = 0; mt < 5; ++mt) {
                acc[mt][nt] = __builtin_amdgcn_mfma_f32_16x16x32_bf16(af[mt], bh, acc[mt][nt], 0, 0, 0);
                acc[mt][nt] = __builtin_amdgcn_mfma_f32_16x16x32_bf16(af[mt], bm, acc[mt][nt], 0, 0, 0);
                acc[mt][nt] = __builtin_amdgcn_mfma_f32_16x16x32_bf16(af[mt], bl, acc[mt][nt], 0, 0, 0);
            }
        }

        __syncthreads();   // drains vmcnt (B nxt) + lgkm (A nxt); flip safe
        cur = nxt;
    }
#undef STAGE_B
#undef SPIKE_FRAG_STORE

    // --- epilogue: acc -> I_all (+ b1) ---
    const int c0 = l & 15;
    float b1v[4];
#pragma unroll
    for (int nt = 0; nt < 4; ++nt)
        b1v[nt] = b1[(wn << 6) + (nt << 4) + c0];
#pragma unroll
    for (int mt = 0; mt < 5; ++mt) {
#pragma unroll
        for (int nt = 0; nt < 4; ++nt) {
            int col = (wn << 6) + (nt << 4) + c0;
#pragma unroll
            for (int r = 0; r < 4; ++r) {
                int row = m0 + wm * 80 + (mt << 4) + (q << 2) + r;
                I_all[(size_t)row * HID + col] = acc[mt][nt][r] + b1v[nt];
            }
        }
    }
}

// ---------------------------------------------------------------------------
// Fused LIF scan + readout: per block, 4 batch rows (1024 blocks = 4/CU).
// Phase 1: thread h scans 4 rows over t (exact reference op order) -> g in
// LDS. Phase 2: wave wv -> row b0+wv, lane c<47: out = sum_h g[b][h]*Wr[h][c]
// (+ br*(1-2^-10)), h ascending — identical fmaf chain to R13.
// ---------------------------------------------------------------------------
__global__ __launch_bounds__(256) void scanout_k(
        const float* __restrict__ I_all, const float* __restrict__ Wr,
        const float* __restrict__ br, float* __restrict__ out) {
    __shared__ float gl[4 * 256];        // 4 KB
    const int tid = threadIdx.x;
    const int b0  = blockIdx.x << 2;

#pragma unroll
    for (int b = 0; b < 4; ++b) {
        const float* p = I_all + ((size_t)(b0 + b) << 8) + tid;
        float v = 0.f, ga = 0.f, wt = 0.0009765625f;   // 2^-10
#pragma unroll
        for (int t = 0; t < T_STEPS; ++t) {
            float I = p[(size_t)t * BATCH * HID];
            v = v + (I - v) * 0.5f;
            if (v >= 1.0f) { ga += wt; v = 0.f; }
            wt += wt;
        }
        gl[(b << 8) + tid] = ga;
    }
    __syncthreads();

    const int wv = tid >> 6;             // wave -> batch row b0+wv
    const int c  = tid & 63;
    if (c >= NCLS) return;
    const float* gb = &gl[wv << 8];
    float acc = 0.f;
    for (int h4 = 0; h4 < 64; ++h4) {
        float w0 = Wr[((h4 << 2) + 0) * NCLS + c];
        float w1 = Wr[((h4 << 2) + 1) * NCLS + c];
        float w2 = Wr[((h4 << 2) + 2) * NCLS + c];
        float w3 = Wr[((h4 << 2) + 3) * NCLS + c];
        float4 gg = *(const float4*)&gb[h4 << 2];
        acc = fmaf(gg.x, w0, acc);
        acc = fmaf(gg.y, w1, acc);
        acc = fmaf(gg.z, w2, acc);
        acc = fmaf(gg.w, w3, acc);
    }
    float brv = br[c] * 0.9990234375f;
    out[(b0 + wv) * NCLS + c] = acc + brv;
}

extern "C" void kernel_launch(void* const* d_in, const int* in_sizes, int n_in,
                              void* d_out, int out_size, void* d_ws, size_t ws_size,
                              hipStream_t stream) {
    const float* x  = (const float*)d_in[0];
    const float* W1 = (const float*)d_in[1];
    const float* b1 = (const float*)d_in[2];
    const float* Wr = (const float*)d_in[3];
    const float* br = (const float*)d_in[4];
    float* out = (float*)d_out;

    float*    I_all = (float*)   ((char*)d_ws + WS_IALL_OFF);
    uint32_t* spkw  = (uint32_t*)((char*)d_ws + WS_SPK_OFF);
    ushort*   w1hi  = (ushort*)  ((char*)d_ws + WS_W1HI_OFF);
    ushort*   w1md  = (ushort*)  ((char*)d_ws + WS_W1MD_OFF);
    ushort*   w1lo  = (ushort*)  ((char*)d_ws + WS_W1LO_OFF);

    splitk_k<<<HID, 256, 0, stream>>>(W1, w1hi, w1md, w1lo);
    spikegen_k<<<dim3(NROWS / 256, KWORDS), 256, 0, stream>>>(x, spkw);
    fused_gemm_k<<<NROWS / M_TILE, 512, 0, stream>>>(w1hi, w1md, w1lo, b1, spkw, I_all);
    scanout_k<<<BATCH / 4, 256, 0, stream>>>(I_all, Wr, br, out);
}